// Round 2
// baseline (16331.842 us; speedup 1.0000x reference)
//
#include <hip/hip_runtime.h>
#include <hip/hip_cooperative_groups.h>

namespace cg = cooperative_groups;

#define HID    2048
#define G3     6144   // 3*HID
#define NVOCAB 128
#define SEQ    512

__device__ __forceinline__ float sigmoidf_(float x) {
  return 1.f / (1.f + __expf(-x));
}
__device__ __forceinline__ float tanhf_(float x) {
  const float ax = fabsf(x);
  const float e2 = __expf(-2.f * ax);
  return copysignf((1.f - e2) / (1.f + e2), x);
}

// ---------------------------------------------------------------------------
// Kernel 1: GI[v][j] = dot(w_ih[j,:], emb[v,:]) + b_ih[j]
// ---------------------------------------------------------------------------
__global__ __launch_bounds__(256) void gi_precompute(
    const float* __restrict__ emb,
    const float* __restrict__ w_ih,
    const float* __restrict__ b_ih,
    float* __restrict__ GI) {
  __shared__ float sE[64][33];
  __shared__ float sW[64][33];

  const int j0 = blockIdx.x * 64;
  const int v0 = blockIdx.y * 64;
  const int tid = threadIdx.x;
  const int tx = tid & 15;
  const int ty = tid >> 4;
  const int r  = tid >> 3;
  const int c4 = (tid & 7) * 4;

  float acc[4][4] = {};

  for (int k0 = 0; k0 < HID; k0 += 32) {
    __syncthreads();
    float4 eA = *(const float4*)&emb [(size_t)(v0 + r)      * HID + k0 + c4];
    float4 eB = *(const float4*)&emb [(size_t)(v0 + r + 32) * HID + k0 + c4];
    float4 wA = *(const float4*)&w_ih[(size_t)(j0 + r)      * HID + k0 + c4];
    float4 wB = *(const float4*)&w_ih[(size_t)(j0 + r + 32) * HID + k0 + c4];
    sE[r][c4+0] = eA.x; sE[r][c4+1] = eA.y; sE[r][c4+2] = eA.z; sE[r][c4+3] = eA.w;
    sE[r+32][c4+0] = eB.x; sE[r+32][c4+1] = eB.y; sE[r+32][c4+2] = eB.z; sE[r+32][c4+3] = eB.w;
    sW[r][c4+0] = wA.x; sW[r][c4+1] = wA.y; sW[r][c4+2] = wA.z; sW[r][c4+3] = wA.w;
    sW[r+32][c4+0] = wB.x; sW[r+32][c4+1] = wB.y; sW[r+32][c4+2] = wB.z; sW[r+32][c4+3] = wB.w;
    __syncthreads();

    #pragma unroll
    for (int kk = 0; kk < 32; ++kk) {
      float e0 = sE[ty*4+0][kk], e1 = sE[ty*4+1][kk];
      float e2 = sE[ty*4+2][kk], e3 = sE[ty*4+3][kk];
      float w0 = sW[tx*4+0][kk], w1 = sW[tx*4+1][kk];
      float w2 = sW[tx*4+2][kk], w3 = sW[tx*4+3][kk];
      acc[0][0] += e0*w0; acc[0][1] += e0*w1; acc[0][2] += e0*w2; acc[0][3] += e0*w3;
      acc[1][0] += e1*w0; acc[1][1] += e1*w1; acc[1][2] += e1*w2; acc[1][3] += e1*w3;
      acc[2][0] += e2*w0; acc[2][1] += e2*w1; acc[2][2] += e2*w2; acc[2][3] += e2*w3;
      acc[3][0] += e3*w0; acc[3][1] += e3*w1; acc[3][2] += e3*w2; acc[3][3] += e3*w3;
    }
  }

  #pragma unroll
  for (int a = 0; a < 4; ++a)
    #pragma unroll
    for (int b = 0; b < 4; ++b) {
      const int j = j0 + tx*4 + b;
      GI[(size_t)(v0 + ty*4 + a) * G3 + j] = acc[a][b] + b_ih[j];
    }
}

// ---------------------------------------------------------------------------
// Cooperative persistent GRU: 256 blocks x 256 threads (1 block/CU needed).
// Each wave owns hidden indices i0 and i0+1024 (6 rows of W_hh).
// ---------------------------------------------------------------------------
__global__ __launch_bounds__(256, 2) void gru_coop(
    const float* __restrict__ GI,
    const float* __restrict__ Whh,
    const float* __restrict__ bhh,
    const int*   __restrict__ inputs,
    const float* __restrict__ wout,
    const float* __restrict__ bout,
    float* hbuf,
    float* out,
    const float* __restrict__ hx) {
  cg::grid_group grid = cg::this_grid();

  __shared__ int s_inp[SEQ];
  for (int k = threadIdx.x; k < SEQ; k += 256) s_inp[k] = inputs[k];
  __syncthreads();

  const int lane = threadIdx.x & 63;
  const int wv   = threadIdx.x >> 6;
  const int i0 = blockIdx.x * 4 + wv;   // 0..1023
  const int i1 = i0 + 1024;             // 1024..2047

  float* h0 = hbuf;
  float* h1 = hbuf + HID;
  if (lane == 0) { h0[i0] = hx[i0]; h0[i1] = hx[i1]; }

  const float br0 = bhh[i0], bz0 = bhh[i0+HID], bn0 = bhh[i0+2*HID];
  const float br1 = bhh[i1], bz1 = bhh[i1+HID], bn1 = bhh[i1+2*HID];
  const float4* wr0 = (const float4*)(Whh + (size_t)i0*HID);
  const float4* wz0 = (const float4*)(Whh + (size_t)(i0+HID)*HID);
  const float4* wn0 = (const float4*)(Whh + (size_t)(i0+2*HID)*HID);
  const float4* wr1 = (const float4*)(Whh + (size_t)i1*HID);
  const float4* wz1 = (const float4*)(Whh + (size_t)(i1+HID)*HID);
  const float4* wn1 = (const float4*)(Whh + (size_t)(i1+2*HID)*HID);

  float* hc = h0;
  float* hn = h1;
  grid.sync();

  for (int t = 0; t < SEQ; ++t) {
    const int v = s_inp[t];
    const float* gi = GI + (size_t)v * G3;
    const float4* hv = (const float4*)hc;

    float ar0=0.f, az0=0.f, an0=0.f, ar1=0.f, az1=0.f, an1=0.f;
    #pragma unroll
    for (int c = 0; c < 8; ++c) {
      const int idx = c*64 + lane;
      const float4 h4 = hv[idx];
      float4 a;
      a = wr0[idx]; ar0 += a.x*h4.x + a.y*h4.y + a.z*h4.z + a.w*h4.w;
      a = wz0[idx]; az0 += a.x*h4.x + a.y*h4.y + a.z*h4.z + a.w*h4.w;
      a = wn0[idx]; an0 += a.x*h4.x + a.y*h4.y + a.z*h4.z + a.w*h4.w;
      a = wr1[idx]; ar1 += a.x*h4.x + a.y*h4.y + a.z*h4.z + a.w*h4.w;
      a = wz1[idx]; az1 += a.x*h4.x + a.y*h4.y + a.z*h4.z + a.w*h4.w;
      a = wn1[idx]; an1 += a.x*h4.x + a.y*h4.y + a.z*h4.z + a.w*h4.w;
    }

    // prefetch scalars (wave-uniform broadcast loads) to overlap the reduce
    const float gir0 = gi[i0], giz0 = gi[i0+HID], gin0 = gi[i0+2*HID];
    const float gir1 = gi[i1], giz1 = gi[i1+HID], gin1 = gi[i1+2*HID];
    const float hp0 = hc[i0], hp1 = hc[i1];

    #pragma unroll
    for (int m = 32; m > 0; m >>= 1) {
      ar0 += __shfl_xor(ar0, m); az0 += __shfl_xor(az0, m); an0 += __shfl_xor(an0, m);
      ar1 += __shfl_xor(ar1, m); az1 += __shfl_xor(az1, m); an1 += __shfl_xor(an1, m);
    }

    if (lane == 0) {
      const float r0 = sigmoidf_(gir0 + ar0 + br0);
      const float z0 = sigmoidf_(giz0 + az0 + bz0);
      const float n0 = tanhf_(gin0 + r0 * (an0 + bn0));
      hn[i0] = (1.f - z0) * n0 + z0 * hp0;
      const float r1 = sigmoidf_(gir1 + ar1 + br1);
      const float z1 = sigmoidf_(giz1 + az1 + bz1);
      const float n1 = tanhf_(gin1 + r1 * (an1 + bn1));
      hn[i1] = (1.f - z1) * n1 + z1 * hp1;
    }
    grid.sync();
    float* tp = hc; hc = hn; hn = tp;
  }

  if (blockIdx.x == 0) {
    __shared__ float logits[2];
    if (wv < 2) {
      const float4* wo = (const float4*)(wout + (size_t)wv * HID);
      const float4* hv = (const float4*)hc;
      float acc = 0.f;
      #pragma unroll
      for (int c = 0; c < 8; ++c) {
        const int idx = c*64 + lane;
        const float4 a  = wo[idx];
        const float4 h4 = hv[idx];
        acc += a.x*h4.x + a.y*h4.y + a.z*h4.z + a.w*h4.w;
      }
      #pragma unroll
      for (int m = 32; m > 0; m >>= 1) acc += __shfl_xor(acc, m);
      if (lane == 0) logits[wv] = acc + bout[wv];
    }
    __syncthreads();
    if (threadIdx.x == 0) {
      const float l0 = logits[0], l1 = logits[1];
      const float mx = fmaxf(l0, l1);
      const float lse = mx + logf(expf(l0 - mx) + expf(l1 - mx));
      out[0] = l0 - lse;
      out[1] = l1 - lse;
    }
  }
}

// ---------------------------------------------------------------------------
// Fallback (non-cooperative) path: one kernel per timestep.
// ---------------------------------------------------------------------------
__global__ __launch_bounds__(256) void gru_step_fb(
    const float* __restrict__ GI,
    const float* __restrict__ Whh,
    const float* __restrict__ bhh,
    const int*   __restrict__ inputs, int t,
    const float* __restrict__ h_in,
    float* __restrict__ h_out) {
  const int lane = threadIdx.x & 63;
  const int wv   = threadIdx.x >> 6;
  const int i = blockIdx.x * 4 + wv;   // 0..2047
  const int v = inputs[t];

  const float4* hv = (const float4*)h_in;
  const float4* wr = (const float4*)(Whh + (size_t)i*HID);
  const float4* wz = (const float4*)(Whh + (size_t)(i+HID)*HID);
  const float4* wn = (const float4*)(Whh + (size_t)(i+2*HID)*HID);

  float ar=0.f, az=0.f, an=0.f;
  #pragma unroll
  for (int c = 0; c < 8; ++c) {
    const int idx = c*64 + lane;
    const float4 h4 = hv[idx];
    float4 a;
    a = wr[idx]; ar += a.x*h4.x + a.y*h4.y + a.z*h4.z + a.w*h4.w;
    a = wz[idx]; az += a.x*h4.x + a.y*h4.y + a.z*h4.z + a.w*h4.w;
    a = wn[idx]; an += a.x*h4.x + a.y*h4.y + a.z*h4.z + a.w*h4.w;
  }
  #pragma unroll
  for (int m = 32; m > 0; m >>= 1) {
    ar += __shfl_xor(ar, m); az += __shfl_xor(az, m); an += __shfl_xor(an, m);
  }
  if (lane == 0) {
    const float* gi = GI + (size_t)v * G3;
    const float r = sigmoidf_(gi[i] + ar + bhh[i]);
    const float z = sigmoidf_(gi[i+HID] + az + bhh[i+HID]);
    const float n = tanhf_(gi[i+2*HID] + r * (an + bhh[i+2*HID]));
    h_out[i] = (1.f - z) * n + z * h_in[i];
  }
}

__global__ void gru_out_fb(const float* __restrict__ h,
                           const float* __restrict__ wout,
                           const float* __restrict__ bout,
                           float* out) {
  __shared__ float logits[2];
  const int lane = threadIdx.x & 63;
  const int wv   = threadIdx.x >> 6;
  if (wv < 2) {
    const float4* wo = (const float4*)(wout + (size_t)wv * HID);
    const float4* hv = (const float4*)h;
    float acc = 0.f;
    #pragma unroll
    for (int c = 0; c < 8; ++c) {
      const int idx = c*64 + lane;
      const float4 a  = wo[idx];
      const float4 h4 = hv[idx];
      acc += a.x*h4.x + a.y*h4.y + a.z*h4.z + a.w*h4.w;
    }
    #pragma unroll
    for (int m = 32; m > 0; m >>= 1) acc += __shfl_xor(acc, m);
    if (lane == 0) logits[wv] = acc + bout[wv];
  }
  __syncthreads();
  if (threadIdx.x == 0) {
    const float l0 = logits[0], l1 = logits[1];
    const float mx = fmaxf(l0, l1);
    const float lse = mx + logf(expf(l0 - mx) + expf(l1 - mx));
    out[0] = l0 - lse;
    out[1] = l1 - lse;
  }
}

// ---------------------------------------------------------------------------
extern "C" void kernel_launch(void* const* d_in, const int* in_sizes, int n_in,
                              void* d_out, int out_size, void* d_ws, size_t ws_size,
                              hipStream_t stream) {
  const int*   inputs = (const int*)  d_in[0];
  const float* hx     = (const float*)d_in[1];
  const float* emb    = (const float*)d_in[2];
  const float* w_ih   = (const float*)d_in[3];
  const float* w_hh   = (const float*)d_in[4];
  const float* b_ih   = (const float*)d_in[5];
  const float* b_hh   = (const float*)d_in[6];
  const float* w_out  = (const float*)d_in[7];
  const float* b_out  = (const float*)d_in[8];
  float* out = (float*)d_out;

  float* GI = (float*)d_ws;                    // 128*6144 floats (3.1 MB)
  float* h0 = GI + (size_t)NVOCAB * G3;        // HID floats
  float* h1 = h0 + HID;                        // HID floats

  gi_precompute<<<dim3(G3/64, NVOCAB/64), 256, 0, stream>>>(emb, w_ih, b_ih, GI);

  float* hbufp = h0;
  void* args[] = { (void*)&GI, (void*)&w_hh, (void*)&b_hh, (void*)&inputs,
                   (void*)&w_out, (void*)&b_out, (void*)&hbufp, (void*)&out,
                   (void*)&hx };
  hipError_t ce = hipLaunchCooperativeKernel((void*)gru_coop, dim3(256), dim3(256),
                                             args, 0, stream);
  if (ce != hipSuccess) {
    // Non-cooperative fallback: one launch per timestep, ping-pong h.
    const float* hin = hx;
    for (int t = 0; t < SEQ; ++t) {
      float* hout = (t & 1) ? h1 : h0;
      gru_step_fb<<<512, 256, 0, stream>>>(GI, w_hh, b_hh, inputs, t, hin, hout);
      hin = hout;
    }
    gru_out_fb<<<1, 128, 0, stream>>>(hin, w_out, b_out, out);
  }
}

// Round 3
// 4319.473 us; speedup vs baseline: 3.7810x; 3.7810x over previous
//
#include <hip/hip_runtime.h>

#define HID    2048
#define G3     6144   // 3*HID
#define NVOCAB 128
#define SEQ    512
#define NBLK   256
#define FLAG_STRIDE 16   // dwords: 64B between flag slots

__device__ __forceinline__ float sigmoidf_(float x) {
  return 1.f / (1.f + __expf(-x));
}
__device__ __forceinline__ float tanhf_(float x) {
  const float ax = fabsf(x);
  const float e2 = __expf(-2.f * ax);
  return copysignf((1.f - e2) / (1.f + e2), x);
}

// ---------------------------------------------------------------------------
// Kernel 1: GI[v][j] = dot(w_ih[j,:], emb[v,:]) + b_ih[j]
// ---------------------------------------------------------------------------
__global__ __launch_bounds__(256) void gi_precompute(
    const float* __restrict__ emb,
    const float* __restrict__ w_ih,
    const float* __restrict__ b_ih,
    float* __restrict__ GI) {
  __shared__ float sE[64][33];
  __shared__ float sW[64][33];

  const int j0 = blockIdx.x * 64;
  const int v0 = blockIdx.y * 64;
  const int tid = threadIdx.x;
  const int tx = tid & 15;
  const int ty = tid >> 4;
  const int r  = tid >> 3;
  const int c4 = (tid & 7) * 4;

  float acc[4][4] = {};

  for (int k0 = 0; k0 < HID; k0 += 32) {
    __syncthreads();
    float4 eA = *(const float4*)&emb [(size_t)(v0 + r)      * HID + k0 + c4];
    float4 eB = *(const float4*)&emb [(size_t)(v0 + r + 32) * HID + k0 + c4];
    float4 wA = *(const float4*)&w_ih[(size_t)(j0 + r)      * HID + k0 + c4];
    float4 wB = *(const float4*)&w_ih[(size_t)(j0 + r + 32) * HID + k0 + c4];
    sE[r][c4+0] = eA.x; sE[r][c4+1] = eA.y; sE[r][c4+2] = eA.z; sE[r][c4+3] = eA.w;
    sE[r+32][c4+0] = eB.x; sE[r+32][c4+1] = eB.y; sE[r+32][c4+2] = eB.z; sE[r+32][c4+3] = eB.w;
    sW[r][c4+0] = wA.x; sW[r][c4+1] = wA.y; sW[r][c4+2] = wA.z; sW[r][c4+3] = wA.w;
    sW[r+32][c4+0] = wB.x; sW[r+32][c4+1] = wB.y; sW[r+32][c4+2] = wB.z; sW[r+32][c4+3] = wB.w;
    __syncthreads();

    #pragma unroll
    for (int kk = 0; kk < 32; ++kk) {
      float e0 = sE[ty*4+0][kk], e1 = sE[ty*4+1][kk];
      float e2 = sE[ty*4+2][kk], e3 = sE[ty*4+3][kk];
      float w0 = sW[tx*4+0][kk], w1 = sW[tx*4+1][kk];
      float w2 = sW[tx*4+2][kk], w3 = sW[tx*4+3][kk];
      acc[0][0] += e0*w0; acc[0][1] += e0*w1; acc[0][2] += e0*w2; acc[0][3] += e0*w3;
      acc[1][0] += e1*w0; acc[1][1] += e1*w1; acc[1][2] += e1*w2; acc[1][3] += e1*w3;
      acc[2][0] += e2*w0; acc[2][1] += e2*w1; acc[2][2] += e2*w2; acc[2][3] += e2*w3;
      acc[3][0] += e3*w0; acc[3][1] += e3*w1; acc[3][2] += e3*w2; acc[3][3] += e3*w3;
    }
  }

  #pragma unroll
  for (int a = 0; a < 4; ++a)
    #pragma unroll
    for (int b = 0; b < 4; ++b) {
      const int j = j0 + tx*4 + b;
      GI[(size_t)(v0 + ty*4 + a) * G3 + j] = acc[a][b] + b_ih[j];
    }
}

// ---------------------------------------------------------------------------
// Persistent GRU, weights in registers, custom flag barrier (no cache inv).
// 256 blocks x 256 threads; wave g owns hidden units {g, g+1024}.
// ---------------------------------------------------------------------------
__global__ __launch_bounds__(256, 1) void gru_reg(
    const float* __restrict__ GI,
    const float* __restrict__ Whh,
    const float* __restrict__ bhh,
    const int*   __restrict__ inputs,
    const float* __restrict__ wout,
    const float* __restrict__ bout,
    float* __restrict__ hbuf,       // 2*HID floats
    unsigned* __restrict__ flags,   // NBLK*FLAG_STRIDE dwords
    float* __restrict__ out,
    const float* __restrict__ hx) {

  __shared__ int s_inp[SEQ];
  for (int k = threadIdx.x; k < SEQ; k += 256) s_inp[k] = inputs[k];

  const int lane = threadIdx.x & 63;
  const int wv   = threadIdx.x >> 6;
  const int i0 = blockIdx.x * 4 + wv;   // 0..1023
  const int i1 = i0 + 1024;             // 1024..2047

  // ---- preload 6 W_hh rows into registers (192 VGPRs/lane) ----
  float w_r0[32], w_z0[32], w_n0[32], w_r1[32], w_z1[32], w_n1[32];
  {
    const float* pr0 = Whh + (size_t)i0 * HID;
    const float* pz0 = Whh + (size_t)(i0 + HID) * HID;
    const float* pn0 = Whh + (size_t)(i0 + 2*HID) * HID;
    const float* pr1 = Whh + (size_t)i1 * HID;
    const float* pz1 = Whh + (size_t)(i1 + HID) * HID;
    const float* pn1 = Whh + (size_t)(i1 + 2*HID) * HID;
    #pragma unroll
    for (int c = 0; c < 32; ++c) {
      const int k = c * 64 + lane;
      w_r0[c] = pr0[k]; w_z0[c] = pz0[k]; w_n0[c] = pn0[k];
      w_r1[c] = pr1[k]; w_z1[c] = pz1[k]; w_n1[c] = pn1[k];
    }
  }

  const float br0 = bhh[i0], bz0 = bhh[i0+HID], bn0 = bhh[i0+2*HID];
  const float br1 = bhh[i1], bz1 = bhh[i1+HID], bn1 = bhh[i1+2*HID];

  float* hb0 = hbuf;
  float* hb1 = hbuf + HID;
  __syncthreads();   // s_inp ready

  #define STEP_BODY(T, FIRST)                                                   \
  {                                                                             \
    const int v = s_inp[(T)];                                                   \
    const float* gi = GI + (size_t)v * G3;                                      \
    const float* hr = (FIRST) ? hx : (((T) & 1) ? hb0 : hb1);                   \
    float* hw = ((T) & 1) ? hb1 : hb0;                                          \
    float hvals[32];                                                            \
    _Pragma("unroll")                                                           \
    for (int c = 0; c < 32; ++c) {                                              \
      const int k = c * 64 + lane;                                              \
      if (FIRST) hvals[c] = hr[k];                                              \
      else hvals[c] = __hip_atomic_load(hr + k, __ATOMIC_RELAXED,               \
                                        __HIP_MEMORY_SCOPE_AGENT);              \
    }                                                                           \
    float hp0, hp1;                                                             \
    if (FIRST) { hp0 = hr[i0]; hp1 = hr[i1]; }                                  \
    else {                                                                      \
      hp0 = __hip_atomic_load(hr + i0, __ATOMIC_RELAXED, __HIP_MEMORY_SCOPE_AGENT); \
      hp1 = __hip_atomic_load(hr + i1, __ATOMIC_RELAXED, __HIP_MEMORY_SCOPE_AGENT); \
    }                                                                           \
    const float gir0 = gi[i0], giz0 = gi[i0+HID], gin0 = gi[i0+2*HID];          \
    const float gir1 = gi[i1], giz1 = gi[i1+HID], gin1 = gi[i1+2*HID];          \
    float ar0=0.f, az0=0.f, an0=0.f, ar1=0.f, az1=0.f, an1=0.f;                 \
    _Pragma("unroll")                                                           \
    for (int c = 0; c < 32; ++c) {                                              \
      const float hv = hvals[c];                                                \
      ar0 = fmaf(w_r0[c], hv, ar0);                                             \
      az0 = fmaf(w_z0[c], hv, az0);                                             \
      an0 = fmaf(w_n0[c], hv, an0);                                             \
      ar1 = fmaf(w_r1[c], hv, ar1);                                             \
      az1 = fmaf(w_z1[c], hv, az1);                                             \
      an1 = fmaf(w_n1[c], hv, an1);                                             \
    }                                                                           \
    _Pragma("unroll")                                                           \
    for (int m = 32; m > 0; m >>= 1) {                                          \
      ar0 += __shfl_xor(ar0, m); az0 += __shfl_xor(az0, m);                     \
      an0 += __shfl_xor(an0, m); ar1 += __shfl_xor(ar1, m);                     \
      az1 += __shfl_xor(az1, m); an1 += __shfl_xor(an1, m);                     \
    }                                                                           \
    if (lane == 0) {                                                            \
      const float r0 = sigmoidf_(gir0 + ar0 + br0);                             \
      const float z0 = sigmoidf_(giz0 + az0 + bz0);                             \
      const float n0 = tanhf_(gin0 + r0 * (an0 + bn0));                         \
      const float h0n = (1.f - z0) * n0 + z0 * hp0;                             \
      const float r1 = sigmoidf_(gir1 + ar1 + br1);                             \
      const float z1 = sigmoidf_(giz1 + az1 + bz1);                             \
      const float n1 = tanhf_(gin1 + r1 * (an1 + bn1));                         \
      const float h1n = (1.f - z1) * n1 + z1 * hp1;                             \
      __hip_atomic_store(hw + i0, h0n, __ATOMIC_RELAXED, __HIP_MEMORY_SCOPE_AGENT); \
      __hip_atomic_store(hw + i1, h1n, __ATOMIC_RELAXED, __HIP_MEMORY_SCOPE_AGENT); \
    }                                                                           \
    /* ---- flag barrier (no cache maintenance) ---- */                         \
    asm volatile("s_waitcnt vmcnt(0)" ::: "memory");                            \
    __syncthreads();                                                            \
    if (threadIdx.x == 0)                                                       \
      __hip_atomic_store(flags + blockIdx.x * FLAG_STRIDE, (unsigned)((T)+1),   \
                         __ATOMIC_RELAXED, __HIP_MEMORY_SCOPE_AGENT);           \
    while (__hip_atomic_load(flags + threadIdx.x * FLAG_STRIDE,                 \
                             __ATOMIC_RELAXED, __HIP_MEMORY_SCOPE_AGENT)        \
           != (unsigned)((T)+1))                                                \
      __builtin_amdgcn_s_sleep(1);                                              \
    __syncthreads();                                                            \
  }

  STEP_BODY(0, true)
  for (int t = 1; t < SEQ; ++t) {
    STEP_BODY(t, false)
  }
  #undef STEP_BODY

  // ---- final projection + log_softmax (block 0) ----
  if (blockIdx.x == 0) {
    __shared__ float logits[2];
    const float* hf = hb1;   // step 511 wrote hb[511&1] = hb1
    if (wv < 2) {
      const float* wo = wout + (size_t)wv * HID;
      float acc = 0.f;
      #pragma unroll
      for (int c = 0; c < 32; ++c) {
        const int k = c * 64 + lane;
        const float hv = __hip_atomic_load(hf + k, __ATOMIC_RELAXED,
                                           __HIP_MEMORY_SCOPE_AGENT);
        acc = fmaf(wo[k], hv, acc);
      }
      #pragma unroll
      for (int m = 32; m > 0; m >>= 1) acc += __shfl_xor(acc, m);
      if (lane == 0) logits[wv] = acc + bout[wv];
    }
    __syncthreads();
    if (threadIdx.x == 0) {
      const float l0 = logits[0], l1 = logits[1];
      const float mx = fmaxf(l0, l1);
      const float lse = mx + logf(expf(l0 - mx) + expf(l1 - mx));
      out[0] = l0 - lse;
      out[1] = l1 - lse;
    }
  }
}

// ---------------------------------------------------------------------------
// Fallback (non-cooperative) path: one kernel per timestep.
// ---------------------------------------------------------------------------
__global__ __launch_bounds__(256) void gru_step_fb(
    const float* __restrict__ GI,
    const float* __restrict__ Whh,
    const float* __restrict__ bhh,
    const int*   __restrict__ inputs, int t,
    const float* __restrict__ h_in,
    float* __restrict__ h_out) {
  const int lane = threadIdx.x & 63;
  const int wvv  = threadIdx.x >> 6;
  const int i = blockIdx.x * 4 + wvv;
  const int v = inputs[t];

  const float4* hv = (const float4*)h_in;
  const float4* wr = (const float4*)(Whh + (size_t)i*HID);
  const float4* wz = (const float4*)(Whh + (size_t)(i+HID)*HID);
  const float4* wn = (const float4*)(Whh + (size_t)(i+2*HID)*HID);

  float ar=0.f, az=0.f, an=0.f;
  #pragma unroll
  for (int c = 0; c < 8; ++c) {
    const int idx = c*64 + lane;
    const float4 h4 = hv[idx];
    float4 a;
    a = wr[idx]; ar += a.x*h4.x + a.y*h4.y + a.z*h4.z + a.w*h4.w;
    a = wz[idx]; az += a.x*h4.x + a.y*h4.y + a.z*h4.z + a.w*h4.w;
    a = wn[idx]; an += a.x*h4.x + a.y*h4.y + a.z*h4.z + a.w*h4.w;
  }
  #pragma unroll
  for (int m = 32; m > 0; m >>= 1) {
    ar += __shfl_xor(ar, m); az += __shfl_xor(az, m); an += __shfl_xor(an, m);
  }
  if (lane == 0) {
    const float* gi = GI + (size_t)v * G3;
    const float r = sigmoidf_(gi[i] + ar + bhh[i]);
    const float z = sigmoidf_(gi[i+HID] + az + bhh[i+HID]);
    const float n = tanhf_(gi[i+2*HID] + r * (an + bhh[i+2*HID]));
    h_out[i] = (1.f - z) * n + z * h_in[i];
  }
}

__global__ void gru_out_fb(const float* __restrict__ h,
                           const float* __restrict__ wout,
                           const float* __restrict__ bout,
                           float* out) {
  __shared__ float logits[2];
  const int lane = threadIdx.x & 63;
  const int wvv  = threadIdx.x >> 6;
  if (wvv < 2) {
    const float4* wo = (const float4*)(wout + (size_t)wvv * HID);
    const float4* hv = (const float4*)h;
    float acc = 0.f;
    #pragma unroll
    for (int c = 0; c < 8; ++c) {
      const int idx = c*64 + lane;
      const float4 a  = wo[idx];
      const float4 h4 = hv[idx];
      acc += a.x*h4.x + a.y*h4.y + a.z*h4.z + a.w*h4.w;
    }
    #pragma unroll
    for (int m = 32; m > 0; m >>= 1) acc += __shfl_xor(acc, m);
    if (lane == 0) logits[wvv] = acc + bout[wvv];
  }
  __syncthreads();
  if (threadIdx.x == 0) {
    const float l0 = logits[0], l1 = logits[1];
    const float mx = fmaxf(l0, l1);
    const float lse = mx + logf(expf(l0 - mx) + expf(l1 - mx));
    out[0] = l0 - lse;
    out[1] = l1 - lse;
  }
}

// ---------------------------------------------------------------------------
extern "C" void kernel_launch(void* const* d_in, const int* in_sizes, int n_in,
                              void* d_out, int out_size, void* d_ws, size_t ws_size,
                              hipStream_t stream) {
  const int*   inputs = (const int*)  d_in[0];
  const float* hx     = (const float*)d_in[1];
  const float* emb    = (const float*)d_in[2];
  const float* w_ih   = (const float*)d_in[3];
  const float* w_hh   = (const float*)d_in[4];
  const float* b_ih   = (const float*)d_in[5];
  const float* b_hh   = (const float*)d_in[6];
  const float* w_out  = (const float*)d_in[7];
  const float* b_out  = (const float*)d_in[8];
  float* out = (float*)d_out;

  float*    GI    = (float*)d_ws;                       // 128*6144 f32 (3.1 MB)
  float*    hbuf  = GI + (size_t)NVOCAB * G3;           // 2*HID f32
  unsigned* flags = (unsigned*)(hbuf + 2 * HID);        // 256*16 dwords (16 KB)

  gi_precompute<<<dim3(G3/64, NVOCAB/64), 256, 0, stream>>>(emb, w_ih, b_ih, GI);

  void* args[] = { (void*)&GI, (void*)&w_hh, (void*)&b_hh, (void*)&inputs,
                   (void*)&w_out, (void*)&b_out, (void*)&hbuf, (void*)&flags,
                   (void*)&out, (void*)&hx };
  hipError_t ce = hipLaunchCooperativeKernel((void*)gru_reg, dim3(NBLK), dim3(256),
                                             args, 0, stream);
  if (ce != hipSuccess) {
    float* h0 = hbuf;
    float* h1 = hbuf + HID;
    const float* hin = hx;
    for (int t = 0; t < SEQ; ++t) {
      float* hout = (t & 1) ? h1 : h0;
      gru_step_fb<<<512, 256, 0, stream>>>(GI, w_hh, b_hh, inputs, t, hin, hout);
      hin = hout;
    }
    gru_out_fb<<<1, 128, 0, stream>>>(hin, w_out, b_out, out);
  }
}

// Round 4
// 2244.628 us; speedup vs baseline: 7.2760x; 1.9244x over previous
//
#include <hip/hip_runtime.h>

#define HID    2048
#define G3     6144   // 3*HID
#define NVOCAB 128
#define SEQ    512
#define NBLK   256
#define FLAG_STRIDE 16   // dwords: 64B between flag slots

__device__ __forceinline__ float sigmoidf_(float x) {
  return 1.f / (1.f + __expf(-x));
}
__device__ __forceinline__ float tanhf_(float x) {
  const float ax = fabsf(x);
  const float e2 = __expf(-2.f * ax);
  return copysignf((1.f - e2) / (1.f + e2), x);
}

// ---------------------------------------------------------------------------
// Kernel 1: GI[v][j] = dot(w_ih[j,:], emb[v,:]) + b_ih[j]
// ---------------------------------------------------------------------------
__global__ __launch_bounds__(256) void gi_precompute(
    const float* __restrict__ emb,
    const float* __restrict__ w_ih,
    const float* __restrict__ b_ih,
    float* __restrict__ GI) {
  __shared__ float sE[64][33];
  __shared__ float sW[64][33];

  const int j0 = blockIdx.x * 64;
  const int v0 = blockIdx.y * 64;
  const int tid = threadIdx.x;
  const int tx = tid & 15;
  const int ty = tid >> 4;
  const int r  = tid >> 3;
  const int c4 = (tid & 7) * 4;

  float acc[4][4] = {};

  for (int k0 = 0; k0 < HID; k0 += 32) {
    __syncthreads();
    float4 eA = *(const float4*)&emb [(size_t)(v0 + r)      * HID + k0 + c4];
    float4 eB = *(const float4*)&emb [(size_t)(v0 + r + 32) * HID + k0 + c4];
    float4 wA = *(const float4*)&w_ih[(size_t)(j0 + r)      * HID + k0 + c4];
    float4 wB = *(const float4*)&w_ih[(size_t)(j0 + r + 32) * HID + k0 + c4];
    sE[r][c4+0] = eA.x; sE[r][c4+1] = eA.y; sE[r][c4+2] = eA.z; sE[r][c4+3] = eA.w;
    sE[r+32][c4+0] = eB.x; sE[r+32][c4+1] = eB.y; sE[r+32][c4+2] = eB.z; sE[r+32][c4+3] = eB.w;
    sW[r][c4+0] = wA.x; sW[r][c4+1] = wA.y; sW[r][c4+2] = wA.z; sW[r][c4+3] = wA.w;
    sW[r+32][c4+0] = wB.x; sW[r+32][c4+1] = wB.y; sW[r+32][c4+2] = wB.z; sW[r+32][c4+3] = wB.w;
    __syncthreads();

    #pragma unroll
    for (int kk = 0; kk < 32; ++kk) {
      float e0 = sE[ty*4+0][kk], e1 = sE[ty*4+1][kk];
      float e2 = sE[ty*4+2][kk], e3 = sE[ty*4+3][kk];
      float w0 = sW[tx*4+0][kk], w1 = sW[tx*4+1][kk];
      float w2 = sW[tx*4+2][kk], w3 = sW[tx*4+3][kk];
      acc[0][0] += e0*w0; acc[0][1] += e0*w1; acc[0][2] += e0*w2; acc[0][3] += e0*w3;
      acc[1][0] += e1*w0; acc[1][1] += e1*w1; acc[1][2] += e1*w2; acc[1][3] += e1*w3;
      acc[2][0] += e2*w0; acc[2][1] += e2*w1; acc[2][2] += e2*w2; acc[2][3] += e2*w3;
      acc[3][0] += e3*w0; acc[3][1] += e3*w1; acc[3][2] += e3*w2; acc[3][3] += e3*w3;
    }
  }

  #pragma unroll
  for (int a = 0; a < 4; ++a)
    #pragma unroll
    for (int b = 0; b < 4; ++b) {
      const int j = j0 + tx*4 + b;
      GI[(size_t)(v0 + ty*4 + a) * G3 + j] = acc[a][b] + b_ih[j];
    }
}

// ---------------------------------------------------------------------------
// Persistent GRU: weights pinned in VGPRs, h staged via LDS, flag barrier.
// 256 blocks x 256 threads; wave g owns hidden units {g, g+1024}.
// ---------------------------------------------------------------------------
__global__ __launch_bounds__(256, 1) void gru_reg(
    const float* __restrict__ GI,
    const float* __restrict__ Whh,
    const float* __restrict__ bhh,
    const int*   __restrict__ inputs,
    const float* __restrict__ wout,
    const float* __restrict__ bout,
    float* __restrict__ hbuf,       // 2*HID floats
    unsigned* __restrict__ flags,   // NBLK*FLAG_STRIDE dwords
    float* __restrict__ out,
    const float* __restrict__ hx) {

  __shared__ int   s_inp[SEQ];
  __shared__ float s_h[HID];
  __shared__ float s_logits[2];

  const int tid  = threadIdx.x;
  const int lane = tid & 63;
  const int wv   = tid >> 6;
  const int i0 = blockIdx.x * 4 + wv;   // 0..1023
  const int i1 = i0 + 1024;             // 1024..2047

  for (int k = tid; k < SEQ; k += 256) s_inp[k] = inputs[k];

  // ---- preload 6 W_hh rows into registers (192 VGPRs/lane), pinned ----
  float w_r0[32], w_z0[32], w_n0[32], w_r1[32], w_z1[32], w_n1[32];
  {
    const float* pr0 = Whh + (size_t)i0 * HID;
    const float* pz0 = Whh + (size_t)(i0 + HID) * HID;
    const float* pn0 = Whh + (size_t)(i0 + 2*HID) * HID;
    const float* pr1 = Whh + (size_t)i1 * HID;
    const float* pz1 = Whh + (size_t)(i1 + HID) * HID;
    const float* pn1 = Whh + (size_t)(i1 + 2*HID) * HID;
    #pragma unroll
    for (int c = 0; c < 8; ++c) {
      const int k = c * 256 + lane * 4;
      *(float4*)&w_r0[c*4] = *(const float4*)&pr0[k];
      *(float4*)&w_z0[c*4] = *(const float4*)&pz0[k];
      *(float4*)&w_n0[c*4] = *(const float4*)&pn0[k];
      *(float4*)&w_r1[c*4] = *(const float4*)&pr1[k];
      *(float4*)&w_z1[c*4] = *(const float4*)&pz1[k];
      *(float4*)&w_n1[c*4] = *(const float4*)&pn1[k];
    }
  }
  // Pin: make each value the output of an opaque asm so the compiler cannot
  // rematerialize the loads inside the step loop (r3: VGPR=132 proved remat).
  #pragma unroll
  for (int c = 0; c < 32; ++c) {
    asm volatile("" : "+v"(w_r0[c]), "+v"(w_z0[c]), "+v"(w_n0[c]),
                      "+v"(w_r1[c]), "+v"(w_z1[c]), "+v"(w_n1[c]));
  }

  const float br0 = bhh[i0], bz0 = bhh[i0+HID], bn0 = bhh[i0+2*HID];
  const float br1 = bhh[i1], bz1 = bhh[i1+HID], bn1 = bhh[i1+2*HID];

  float* hb0 = hbuf;
  float* hb1 = hbuf + HID;
  __syncthreads();   // s_inp ready

  for (int t = 0; t < SEQ; ++t) {
    const int v = s_inp[t];
    const float* gi = GI + (size_t)v * G3;

    // ---- stage h[t] into LDS (coalesced, agent-scope for t>0) ----
    if (t == 0) {
      #pragma unroll
      for (int j = 0; j < 8; ++j) s_h[j*256 + tid] = hx[j*256 + tid];
    } else {
      const float* hr = (t & 1) ? hb0 : hb1;
      float tmp[8];
      #pragma unroll
      for (int j = 0; j < 8; ++j)
        tmp[j] = __hip_atomic_load(hr + j*256 + tid, __ATOMIC_RELAXED,
                                   __HIP_MEMORY_SCOPE_AGENT);
      #pragma unroll
      for (int j = 0; j < 8; ++j) s_h[j*256 + tid] = tmp[j];
    }
    __syncthreads();

    // ---- 6 dot products from LDS h + register weights ----
    float ar0=0.f, az0=0.f, an0=0.f, ar1=0.f, az1=0.f, an1=0.f;
    #pragma unroll
    for (int c = 0; c < 8; ++c) {
      const float4 h4 = *(const float4*)&s_h[c*256 + lane*4];
      ar0 = fmaf(w_r0[c*4+0], h4.x, ar0); ar0 = fmaf(w_r0[c*4+1], h4.y, ar0);
      ar0 = fmaf(w_r0[c*4+2], h4.z, ar0); ar0 = fmaf(w_r0[c*4+3], h4.w, ar0);
      az0 = fmaf(w_z0[c*4+0], h4.x, az0); az0 = fmaf(w_z0[c*4+1], h4.y, az0);
      az0 = fmaf(w_z0[c*4+2], h4.z, az0); az0 = fmaf(w_z0[c*4+3], h4.w, az0);
      an0 = fmaf(w_n0[c*4+0], h4.x, an0); an0 = fmaf(w_n0[c*4+1], h4.y, an0);
      an0 = fmaf(w_n0[c*4+2], h4.z, an0); an0 = fmaf(w_n0[c*4+3], h4.w, an0);
      ar1 = fmaf(w_r1[c*4+0], h4.x, ar1); ar1 = fmaf(w_r1[c*4+1], h4.y, ar1);
      ar1 = fmaf(w_r1[c*4+2], h4.z, ar1); ar1 = fmaf(w_r1[c*4+3], h4.w, ar1);
      az1 = fmaf(w_z1[c*4+0], h4.x, az1); az1 = fmaf(w_z1[c*4+1], h4.y, az1);
      az1 = fmaf(w_z1[c*4+2], h4.z, az1); az1 = fmaf(w_z1[c*4+3], h4.w, az1);
      an1 = fmaf(w_n1[c*4+0], h4.x, an1); an1 = fmaf(w_n1[c*4+1], h4.y, an1);
      an1 = fmaf(w_n1[c*4+2], h4.z, an1); an1 = fmaf(w_n1[c*4+3], h4.w, an1);
    }

    const float gir0 = gi[i0], giz0 = gi[i0+HID], gin0 = gi[i0+2*HID];
    const float gir1 = gi[i1], giz1 = gi[i1+HID], gin1 = gi[i1+2*HID];
    const float hp0 = s_h[i0], hp1 = s_h[i1];

    #pragma unroll
    for (int m = 32; m > 0; m >>= 1) {
      ar0 += __shfl_xor(ar0, m); az0 += __shfl_xor(az0, m); an0 += __shfl_xor(an0, m);
      ar1 += __shfl_xor(ar1, m); az1 += __shfl_xor(az1, m); an1 += __shfl_xor(an1, m);
    }

    float* hw = (t & 1) ? hb1 : hb0;
    if (lane == 0) {
      const float r0 = sigmoidf_(gir0 + ar0 + br0);
      const float z0 = sigmoidf_(giz0 + az0 + bz0);
      const float n0 = tanhf_(gin0 + r0 * (an0 + bn0));
      __hip_atomic_store(hw + i0, (1.f - z0) * n0 + z0 * hp0,
                         __ATOMIC_RELAXED, __HIP_MEMORY_SCOPE_AGENT);
      const float r1 = sigmoidf_(gir1 + ar1 + br1);
      const float z1 = sigmoidf_(giz1 + az1 + bz1);
      const float n1 = tanhf_(gin1 + r1 * (an1 + bn1));
      __hip_atomic_store(hw + i1, (1.f - z1) * n1 + z1 * hp1,
                         __ATOMIC_RELAXED, __HIP_MEMORY_SCOPE_AGENT);
    }

    // ---- flag barrier (no cache maintenance) ----
    asm volatile("s_waitcnt vmcnt(0)" ::: "memory");
    __syncthreads();
    if (tid == 0)
      __hip_atomic_store(flags + blockIdx.x * FLAG_STRIDE, (unsigned)(t + 1),
                         __ATOMIC_RELAXED, __HIP_MEMORY_SCOPE_AGENT);
    while (__hip_atomic_load(flags + tid * FLAG_STRIDE,
                             __ATOMIC_RELAXED, __HIP_MEMORY_SCOPE_AGENT)
           != (unsigned)(t + 1))
      __builtin_amdgcn_s_sleep(1);
    __syncthreads();
  }

  // ---- final projection + log_softmax (block 0) ----
  if (blockIdx.x == 0) {
    const float* hf = hb1;   // step 511 wrote hb1
    if (wv < 2) {
      const float* wo = wout + (size_t)wv * HID;
      float acc = 0.f;
      #pragma unroll
      for (int c = 0; c < 32; ++c) {
        const int k = c * 64 + lane;
        const float hv = __hip_atomic_load(hf + k, __ATOMIC_RELAXED,
                                           __HIP_MEMORY_SCOPE_AGENT);
        acc = fmaf(wo[k], hv, acc);
      }
      #pragma unroll
      for (int m = 32; m > 0; m >>= 1) acc += __shfl_xor(acc, m);
      if (lane == 0) s_logits[wv] = acc + bout[wv];
    }
    __syncthreads();
    if (tid == 0) {
      const float l0 = s_logits[0], l1 = s_logits[1];
      const float mx = fmaxf(l0, l1);
      const float lse = mx + logf(expf(l0 - mx) + expf(l1 - mx));
      out[0] = l0 - lse;
      out[1] = l1 - lse;
    }
  }
}

// ---------------------------------------------------------------------------
// Fallback (non-cooperative) path: one kernel per timestep.
// ---------------------------------------------------------------------------
__global__ __launch_bounds__(256) void gru_step_fb(
    const float* __restrict__ GI,
    const float* __restrict__ Whh,
    const float* __restrict__ bhh,
    const int*   __restrict__ inputs, int t,
    const float* __restrict__ h_in,
    float* __restrict__ h_out) {
  const int lane = threadIdx.x & 63;
  const int wvv  = threadIdx.x >> 6;
  const int i = blockIdx.x * 4 + wvv;
  const int v = inputs[t];

  const float4* hv = (const float4*)h_in;
  const float4* wr = (const float4*)(Whh + (size_t)i*HID);
  const float4* wz = (const float4*)(Whh + (size_t)(i+HID)*HID);
  const float4* wn = (const float4*)(Whh + (size_t)(i+2*HID)*HID);

  float ar=0.f, az=0.f, an=0.f;
  #pragma unroll
  for (int c = 0; c < 8; ++c) {
    const int idx = c*64 + lane;
    const float4 h4 = hv[idx];
    float4 a;
    a = wr[idx]; ar += a.x*h4.x + a.y*h4.y + a.z*h4.z + a.w*h4.w;
    a = wz[idx]; az += a.x*h4.x + a.y*h4.y + a.z*h4.z + a.w*h4.w;
    a = wn[idx]; an += a.x*h4.x + a.y*h4.y + a.z*h4.z + a.w*h4.w;
  }
  #pragma unroll
  for (int m = 32; m > 0; m >>= 1) {
    ar += __shfl_xor(ar, m); az += __shfl_xor(az, m); an += __shfl_xor(an, m);
  }
  if (lane == 0) {
    const float* gi = GI + (size_t)v * G3;
    const float r = sigmoidf_(gi[i] + ar + bhh[i]);
    const float z = sigmoidf_(gi[i+HID] + az + bhh[i+HID]);
    const float n = tanhf_(gi[i+2*HID] + r * (an + bhh[i+2*HID]));
    h_out[i] = (1.f - z) * n + z * h_in[i];
  }
}

__global__ void gru_out_fb(const float* __restrict__ h,
                           const float* __restrict__ wout,
                           const float* __restrict__ bout,
                           float* out) {
  __shared__ float logits[2];
  const int lane = threadIdx.x & 63;
  const int wvv  = threadIdx.x >> 6;
  if (wvv < 2) {
    const float4* wo = (const float4*)(wout + (size_t)wvv * HID);
    const float4* hv = (const float4*)h;
    float acc = 0.f;
    #pragma unroll
    for (int c = 0; c < 8; ++c) {
      const int idx = c*64 + lane;
      const float4 a  = wo[idx];
      const float4 h4 = hv[idx];
      acc += a.x*h4.x + a.y*h4.y + a.z*h4.z + a.w*h4.w;
    }
    #pragma unroll
    for (int m = 32; m > 0; m >>= 1) acc += __shfl_xor(acc, m);
    if (lane == 0) logits[wvv] = acc + bout[wvv];
  }
  __syncthreads();
  if (threadIdx.x == 0) {
    const float l0 = logits[0], l1 = logits[1];
    const float mx = fmaxf(l0, l1);
    const float lse = mx + logf(expf(l0 - mx) + expf(l1 - mx));
    out[0] = l0 - lse;
    out[1] = l1 - lse;
  }
}

// ---------------------------------------------------------------------------
extern "C" void kernel_launch(void* const* d_in, const int* in_sizes, int n_in,
                              void* d_out, int out_size, void* d_ws, size_t ws_size,
                              hipStream_t stream) {
  const int*   inputs = (const int*)  d_in[0];
  const float* hx     = (const float*)d_in[1];
  const float* emb    = (const float*)d_in[2];
  const float* w_ih   = (const float*)d_in[3];
  const float* w_hh   = (const float*)d_in[4];
  const float* b_ih   = (const float*)d_in[5];
  const float* b_hh   = (const float*)d_in[6];
  const float* w_out  = (const float*)d_in[7];
  const float* b_out  = (const float*)d_in[8];
  float* out = (float*)d_out;

  float*    GI    = (float*)d_ws;                       // 128*6144 f32 (3.1 MB)
  float*    hbuf  = GI + (size_t)NVOCAB * G3;           // 2*HID f32
  unsigned* flags = (unsigned*)(hbuf + 2 * HID);        // 256*16 dwords (16 KB)

  gi_precompute<<<dim3(G3/64, NVOCAB/64), 256, 0, stream>>>(emb, w_ih, b_ih, GI);

  void* args[] = { (void*)&GI, (void*)&w_hh, (void*)&b_hh, (void*)&inputs,
                   (void*)&w_out, (void*)&b_out, (void*)&hbuf, (void*)&flags,
                   (void*)&out, (void*)&hx };
  hipError_t ce = hipLaunchCooperativeKernel((void*)gru_reg, dim3(NBLK), dim3(256),
                                             args, 0, stream);
  if (ce != hipSuccess) {
    float* h0 = hbuf;
    float* h1 = hbuf + HID;
    const float* hin = hx;
    for (int t = 0; t < SEQ; ++t) {
      float* hout = (t & 1) ? h1 : h0;
      gru_step_fb<<<512, 256, 0, stream>>>(GI, w_hh, b_hh, inputs, t, hin, hout);
      hin = hout;
    }
    gru_out_fb<<<1, 128, 0, stream>>>(hin, w_out, b_out, out);
  }
}

// Round 5
// 2238.608 us; speedup vs baseline: 7.2955x; 1.0027x over previous
//
#include <hip/hip_runtime.h>

#define HID    2048
#define G3     6144   // 3*HID
#define NVOCAB 128
#define SEQ    512
#define NBLK   256
#define TAGBASE 0x5EED0000u

__device__ __forceinline__ float sigmoidf_(float x) {
  return 1.f / (1.f + __expf(-x));
}
__device__ __forceinline__ float tanhf_(float x) {
  const float ax = fabsf(x);
  const float e2 = __expf(-2.f * ax);
  return copysignf((1.f - e2) / (1.f + e2), x);
}

// ---------------------------------------------------------------------------
// Kernel 1: GI[v][j] = dot(w_ih[j,:], emb[v,:]) + b_ih[j]
// ---------------------------------------------------------------------------
__global__ __launch_bounds__(256) void gi_precompute(
    const float* __restrict__ emb,
    const float* __restrict__ w_ih,
    const float* __restrict__ b_ih,
    float* __restrict__ GI) {
  __shared__ float sE[64][33];
  __shared__ float sW[64][33];

  const int j0 = blockIdx.x * 64;
  const int v0 = blockIdx.y * 64;
  const int tid = threadIdx.x;
  const int tx = tid & 15;
  const int ty = tid >> 4;
  const int r  = tid >> 3;
  const int c4 = (tid & 7) * 4;

  float acc[4][4] = {};

  for (int k0 = 0; k0 < HID; k0 += 32) {
    __syncthreads();
    float4 eA = *(const float4*)&emb [(size_t)(v0 + r)      * HID + k0 + c4];
    float4 eB = *(const float4*)&emb [(size_t)(v0 + r + 32) * HID + k0 + c4];
    float4 wA = *(const float4*)&w_ih[(size_t)(j0 + r)      * HID + k0 + c4];
    float4 wB = *(const float4*)&w_ih[(size_t)(j0 + r + 32) * HID + k0 + c4];
    sE[r][c4+0] = eA.x; sE[r][c4+1] = eA.y; sE[r][c4+2] = eA.z; sE[r][c4+3] = eA.w;
    sE[r+32][c4+0] = eB.x; sE[r+32][c4+1] = eB.y; sE[r+32][c4+2] = eB.z; sE[r+32][c4+3] = eB.w;
    sW[r][c4+0] = wA.x; sW[r][c4+1] = wA.y; sW[r][c4+2] = wA.z; sW[r][c4+3] = wA.w;
    sW[r+32][c4+0] = wB.x; sW[r+32][c4+1] = wB.y; sW[r+32][c4+2] = wB.z; sW[r+32][c4+3] = wB.w;
    __syncthreads();

    #pragma unroll
    for (int kk = 0; kk < 32; ++kk) {
      float e0 = sE[ty*4+0][kk], e1 = sE[ty*4+1][kk];
      float e2 = sE[ty*4+2][kk], e3 = sE[ty*4+3][kk];
      float w0 = sW[tx*4+0][kk], w1 = sW[tx*4+1][kk];
      float w2 = sW[tx*4+2][kk], w3 = sW[tx*4+3][kk];
      acc[0][0] += e0*w0; acc[0][1] += e0*w1; acc[0][2] += e0*w2; acc[0][3] += e0*w3;
      acc[1][0] += e1*w0; acc[1][1] += e1*w1; acc[1][2] += e1*w2; acc[1][3] += e1*w3;
      acc[2][0] += e2*w0; acc[2][1] += e2*w1; acc[2][2] += e2*w2; acc[2][3] += e2*w3;
      acc[3][0] += e3*w0; acc[3][1] += e3*w1; acc[3][2] += e3*w2; acc[3][3] += e3*w3;
    }
  }

  #pragma unroll
  for (int a = 0; a < 4; ++a)
    #pragma unroll
    for (int b = 0; b < 4; ++b) {
      const int j = j0 + tx*4 + b;
      GI[(size_t)(v0 + ty*4 + a) * G3 + j] = acc[a][b] + b_ih[j];
    }
}

// ---------------------------------------------------------------------------
// Persistent GRU. Weights pinned in AGPRs, tagged-value h exchange (1 RTT),
// GI scalars software-pipelined. 256 blocks x 256 threads.
// ---------------------------------------------------------------------------
__global__ __launch_bounds__(256, 1) void gru_reg(
    const float* __restrict__ GI,
    const float* __restrict__ Whh,
    const float* __restrict__ bhh,
    const int*   __restrict__ inputs,
    const float* __restrict__ wout,
    const float* __restrict__ bout,
    unsigned long long* __restrict__ bufU,   // 2 * 2048 tagged slots
    unsigned* __restrict__ done,             // 257*16 dwords (done + flag0)
    float* __restrict__ out,
    const float* __restrict__ hx) {

  __shared__ int   s_inp[SEQ];
  __shared__ float s_h[HID];
  __shared__ float s_logits[2];

  const int tid  = threadIdx.x;
  const int lane = tid & 63;
  const int wv   = tid >> 6;
  const int i0 = blockIdx.x * 4 + wv;   // 0..1023
  const int i1 = i0 + 1024;             // 1024..2047
  unsigned* flag0 = done + 256 * 16;

  for (int k = tid; k < SEQ; k += 256) s_inp[k] = inputs[k];

  // ---- preload 6 W_hh rows (192 regs/lane), pin into AGPRs ----
  float w_r0[32], w_z0[32], w_n0[32], w_r1[32], w_z1[32], w_n1[32];
  {
    const float* pr0 = Whh + (size_t)i0 * HID;
    const float* pz0 = Whh + (size_t)(i0 + HID) * HID;
    const float* pn0 = Whh + (size_t)(i0 + 2*HID) * HID;
    const float* pr1 = Whh + (size_t)i1 * HID;
    const float* pz1 = Whh + (size_t)(i1 + HID) * HID;
    const float* pn1 = Whh + (size_t)(i1 + 2*HID) * HID;
    #pragma unroll
    for (int c = 0; c < 8; ++c) {
      const int k = c * 256 + lane * 4;
      *(float4*)&w_r0[c*4] = *(const float4*)&pr0[k];
      *(float4*)&w_z0[c*4] = *(const float4*)&pz0[k];
      *(float4*)&w_n0[c*4] = *(const float4*)&pn0[k];
      *(float4*)&w_r1[c*4] = *(const float4*)&pr1[k];
      *(float4*)&w_z1[c*4] = *(const float4*)&pz1[k];
      *(float4*)&w_n1[c*4] = *(const float4*)&pn1[k];
    }
  }
  // Pin each value into an AGPR (unified file; 192a + ~120v < 512 budget).
  // Opaque asm output -> cannot be rematerialized from memory in the loop.
  #pragma unroll
  for (int c = 0; c < 32; ++c) {
    asm volatile("" : "+a"(w_r0[c]), "+a"(w_z0[c]), "+a"(w_n0[c]),
                      "+a"(w_r1[c]), "+a"(w_z1[c]), "+a"(w_n1[c]));
  }

  const float br0 = bhh[i0], bz0 = bhh[i0+HID], bn0 = bhh[i0+2*HID];
  const float br1 = bhh[i1], bz1 = bhh[i1+HID], bn1 = bhh[i1+2*HID];

  __syncthreads();   // s_inp ready

  // initial GI scalars for step 0
  float g0r, g0z, g0n, g1r, g1z, g1n;
  {
    const float* gp = GI + (size_t)s_inp[0] * G3;
    g0r = gp[i0]; g0z = gp[i0+HID]; g0n = gp[i0+2*HID];
    g1r = gp[i1]; g1z = gp[i1+HID]; g1n = gp[i1+2*HID];
  }

  for (int s = 0; s < SEQ; ++s) {
    // ---- stage h (version s) into LDS ----
    if (s == 0) {
      #pragma unroll
      for (int j = 0; j < 8; ++j) s_h[j*256 + tid] = hx[j*256 + tid];
    } else {
      const unsigned wantTag = TAGBASE | (unsigned)s;
      const unsigned long long* br_ = bufU + (size_t)(s & 1) * HID;
      unsigned pending = 0xFFu;
      while (pending) {
        unsigned long long x[8];
        #pragma unroll
        for (int j = 0; j < 8; ++j)
          if (pending & (1u << j))
            x[j] = __hip_atomic_load(br_ + j*256 + tid, __ATOMIC_RELAXED,
                                     __HIP_MEMORY_SCOPE_AGENT);
        #pragma unroll
        for (int j = 0; j < 8; ++j)
          if ((pending & (1u << j)) && (unsigned)(x[j] >> 32) == wantTag) {
            s_h[j*256 + tid] = __uint_as_float((unsigned)x[j]);
            pending &= ~(1u << j);
          }
      }
    }
    __syncthreads();

    // ---- prefetch next step's GI scalars (independent of h) ----
    float ng0r=g0r, ng0z=g0z, ng0n=g0n, ng1r=g1r, ng1z=g1z, ng1n=g1n;
    if (s + 1 < SEQ) {
      const float* gp = GI + (size_t)s_inp[s+1] * G3;
      ng0r = gp[i0]; ng0z = gp[i0+HID]; ng0n = gp[i0+2*HID];
      ng1r = gp[i1]; ng1z = gp[i1+HID]; ng1n = gp[i1+2*HID];
    }

    // ---- 6 dot products: LDS h x AGPR weights ----
    float ar0=0.f, az0=0.f, an0=0.f, ar1=0.f, az1=0.f, an1=0.f;
    #pragma unroll
    for (int c = 0; c < 8; ++c) {
      const float4 h4 = *(const float4*)&s_h[c*256 + lane*4];
      ar0 = fmaf(w_r0[c*4+0], h4.x, ar0); ar0 = fmaf(w_r0[c*4+1], h4.y, ar0);
      ar0 = fmaf(w_r0[c*4+2], h4.z, ar0); ar0 = fmaf(w_r0[c*4+3], h4.w, ar0);
      az0 = fmaf(w_z0[c*4+0], h4.x, az0); az0 = fmaf(w_z0[c*4+1], h4.y, az0);
      az0 = fmaf(w_z0[c*4+2], h4.z, az0); az0 = fmaf(w_z0[c*4+3], h4.w, az0);
      an0 = fmaf(w_n0[c*4+0], h4.x, an0); an0 = fmaf(w_n0[c*4+1], h4.y, an0);
      an0 = fmaf(w_n0[c*4+2], h4.z, an0); an0 = fmaf(w_n0[c*4+3], h4.w, an0);
      ar1 = fmaf(w_r1[c*4+0], h4.x, ar1); ar1 = fmaf(w_r1[c*4+1], h4.y, ar1);
      ar1 = fmaf(w_r1[c*4+2], h4.z, ar1); ar1 = fmaf(w_r1[c*4+3], h4.w, ar1);
      az1 = fmaf(w_z1[c*4+0], h4.x, az1); az1 = fmaf(w_z1[c*4+1], h4.y, az1);
      az1 = fmaf(w_z1[c*4+2], h4.z, az1); az1 = fmaf(w_z1[c*4+3], h4.w, az1);
      an1 = fmaf(w_n1[c*4+0], h4.x, an1); an1 = fmaf(w_n1[c*4+1], h4.y, an1);
      an1 = fmaf(w_n1[c*4+2], h4.z, an1); an1 = fmaf(w_n1[c*4+3], h4.w, an1);
    }

    const float hp0 = s_h[i0], hp1 = s_h[i1];

    #pragma unroll
    for (int m = 32; m > 0; m >>= 1) {
      ar0 += __shfl_xor(ar0, m); az0 += __shfl_xor(az0, m); an0 += __shfl_xor(an0, m);
      ar1 += __shfl_xor(ar1, m); az1 += __shfl_xor(az1, m); an1 += __shfl_xor(an1, m);
    }

    if (lane == 0) {
      const unsigned tagv = TAGBASE | (unsigned)(s + 1);
      unsigned long long* bw = bufU + (size_t)((s + 1) & 1) * HID;
      const float r0 = sigmoidf_(g0r + ar0 + br0);
      const float z0 = sigmoidf_(g0z + az0 + bz0);
      const float n0 = tanhf_(g0n + r0 * (an0 + bn0));
      const float h0n = (1.f - z0) * n0 + z0 * hp0;
      const float r1 = sigmoidf_(g1r + ar1 + br1);
      const float z1 = sigmoidf_(g1z + az1 + bz1);
      const float n1 = tanhf_(g1n + r1 * (an1 + bn1));
      const float h1n = (1.f - z1) * n1 + z1 * hp1;
      __hip_atomic_store(bw + i0,
          ((unsigned long long)tagv << 32) | (unsigned long long)__float_as_uint(h0n),
          __ATOMIC_RELAXED, __HIP_MEMORY_SCOPE_AGENT);
      __hip_atomic_store(bw + i1,
          ((unsigned long long)tagv << 32) | (unsigned long long)__float_as_uint(h1n),
          __ATOMIC_RELAXED, __HIP_MEMORY_SCOPE_AGENT);
    }

    g0r = ng0r; g0z = ng0z; g0n = ng0n;
    g1r = ng1r; g1z = ng1z; g1n = ng1n;

    __syncthreads();   // protect s_h before next stage-in overwrites it
  }

  // ======================= epilogue + cleanup =======================
  if (blockIdx.x == 0) {
    // stage version 512 (buf0)
    {
      const unsigned wantTag = TAGBASE | (unsigned)SEQ;
      const unsigned long long* br_ = bufU;   // SEQ&1 == 0
      unsigned pending = 0xFFu;
      while (pending) {
        unsigned long long x[8];
        #pragma unroll
        for (int j = 0; j < 8; ++j)
          if (pending & (1u << j))
            x[j] = __hip_atomic_load(br_ + j*256 + tid, __ATOMIC_RELAXED,
                                     __HIP_MEMORY_SCOPE_AGENT);
        #pragma unroll
        for (int j = 0; j < 8; ++j)
          if ((pending & (1u << j)) && (unsigned)(x[j] >> 32) == wantTag) {
            s_h[j*256 + tid] = __uint_as_float((unsigned)x[j]);
            pending &= ~(1u << j);
          }
      }
    }
    __syncthreads();
    if (tid == 0)
      __hip_atomic_store(flag0, 0xD0D0D0D0u, __ATOMIC_RELAXED,
                         __HIP_MEMORY_SCOPE_AGENT);

    // projection + log_softmax from LDS h
    if (wv < 2) {
      const float* wo = wout + (size_t)wv * HID;
      float acc = 0.f;
      #pragma unroll
      for (int c = 0; c < 8; ++c) {
        const float4 h4 = *(const float4*)&s_h[c*256 + lane*4];
        const float4 a4 = *(const float4*)&wo[c*256 + lane*4];
        acc += a4.x*h4.x + a4.y*h4.y + a4.z*h4.z + a4.w*h4.w;
      }
      #pragma unroll
      for (int m = 32; m > 0; m >>= 1) acc += __shfl_xor(acc, m);
      if (lane == 0) s_logits[wv] = acc + bout[wv];
    }
    __syncthreads();
    if (tid == 0) {
      const float l0 = s_logits[0], l1 = s_logits[1];
      const float mx = fmaxf(l0, l1);
      const float lse = mx + logf(expf(l0 - mx) + expf(l1 - mx));
      out[0] = l0 - lse;
      out[1] = l1 - lse;
    }
    // zero own tag slots (units wv and wv+1024)
    if (tid < 8) {
      const int slot = (tid & 3) + (tid >> 2) * 1024;
      __hip_atomic_store(bufU + slot, 0ull, __ATOMIC_RELAXED, __HIP_MEMORY_SCOPE_AGENT);
      __hip_atomic_store(bufU + HID + slot, 0ull, __ATOMIC_RELAXED, __HIP_MEMORY_SCOPE_AGENT);
    }
    // wait for all other blocks, then zero done[] + flag0
    if (tid >= 1) {
      while (__hip_atomic_load(done + tid * 16, __ATOMIC_RELAXED,
                               __HIP_MEMORY_SCOPE_AGENT) != 0xD1D1D1D1u)
        __builtin_amdgcn_s_sleep(8);
    }
    __syncthreads();
    __hip_atomic_store(done + tid * 16, 0u, __ATOMIC_RELAXED, __HIP_MEMORY_SCOPE_AGENT);
    if (tid == 0)
      __hip_atomic_store(flag0, 0u, __ATOMIC_RELAXED, __HIP_MEMORY_SCOPE_AGENT);
  } else {
    if (tid == 0) {
      while (__hip_atomic_load(flag0, __ATOMIC_RELAXED,
                               __HIP_MEMORY_SCOPE_AGENT) != 0xD0D0D0D0u)
        __builtin_amdgcn_s_sleep(8);
    }
    __syncthreads();
    if (tid < 8) {
      const int slot = blockIdx.x * 4 + (tid & 3) + (tid >> 2) * 1024;
      __hip_atomic_store(bufU + slot, 0ull, __ATOMIC_RELAXED, __HIP_MEMORY_SCOPE_AGENT);
      __hip_atomic_store(bufU + HID + slot, 0ull, __ATOMIC_RELAXED, __HIP_MEMORY_SCOPE_AGENT);
    }
    asm volatile("s_waitcnt vmcnt(0)" ::: "memory");
    __syncthreads();
    if (tid == 0)
      __hip_atomic_store(done + blockIdx.x * 16, 0xD1D1D1D1u, __ATOMIC_RELAXED,
                         __HIP_MEMORY_SCOPE_AGENT);
  }
}

// ---------------------------------------------------------------------------
// Fallback (non-cooperative) path: one kernel per timestep.
// ---------------------------------------------------------------------------
__global__ __launch_bounds__(256) void gru_step_fb(
    const float* __restrict__ GI,
    const float* __restrict__ Whh,
    const float* __restrict__ bhh,
    const int*   __restrict__ inputs, int t,
    const float* __restrict__ h_in,
    float* __restrict__ h_out) {
  const int lane = threadIdx.x & 63;
  const int wvv  = threadIdx.x >> 6;
  const int i = blockIdx.x * 4 + wvv;
  const int v = inputs[t];

  const float4* hv = (const float4*)h_in;
  const float4* wr = (const float4*)(Whh + (size_t)i*HID);
  const float4* wz = (const float4*)(Whh + (size_t)(i+HID)*HID);
  const float4* wn = (const float4*)(Whh + (size_t)(i+2*HID)*HID);

  float ar=0.f, az=0.f, an=0.f;
  #pragma unroll
  for (int c = 0; c < 8; ++c) {
    const int idx = c*64 + lane;
    const float4 h4 = hv[idx];
    float4 a;
    a = wr[idx]; ar += a.x*h4.x + a.y*h4.y + a.z*h4.z + a.w*h4.w;
    a = wz[idx]; az += a.x*h4.x + a.y*h4.y + a.z*h4.z + a.w*h4.w;
    a = wn[idx]; an += a.x*h4.x + a.y*h4.y + a.z*h4.z + a.w*h4.w;
  }
  #pragma unroll
  for (int m = 32; m > 0; m >>= 1) {
    ar += __shfl_xor(ar, m); az += __shfl_xor(az, m); an += __shfl_xor(an, m);
  }
  if (lane == 0) {
    const float* gi = GI + (size_t)v * G3;
    const float r = sigmoidf_(gi[i] + ar + bhh[i]);
    const float z = sigmoidf_(gi[i+HID] + az + bhh[i+HID]);
    const float n = tanhf_(gi[i+2*HID] + r * (an + bhh[i+2*HID]));
    h_out[i] = (1.f - z) * n + z * h_in[i];
  }
}

__global__ void gru_out_fb(const float* __restrict__ h,
                           const float* __restrict__ wout,
                           const float* __restrict__ bout,
                           float* out) {
  __shared__ float logits[2];
  const int lane = threadIdx.x & 63;
  const int wvv  = threadIdx.x >> 6;
  if (wvv < 2) {
    const float4* wo = (const float4*)(wout + (size_t)wvv * HID);
    const float4* hv = (const float4*)h;
    float acc = 0.f;
    #pragma unroll
    for (int c = 0; c < 8; ++c) {
      const int idx = c*64 + lane;
      const float4 a  = wo[idx];
      const float4 h4 = hv[idx];
      acc += a.x*h4.x + a.y*h4.y + a.z*h4.z + a.w*h4.w;
    }
    #pragma unroll
    for (int m = 32; m > 0; m >>= 1) acc += __shfl_xor(acc, m);
    if (lane == 0) logits[wvv] = acc + bout[wvv];
  }
  __syncthreads();
  if (threadIdx.x == 0) {
    const float l0 = logits[0], l1 = logits[1];
    const float mx = fmaxf(l0, l1);
    const float lse = mx + logf(expf(l0 - mx) + expf(l1 - mx));
    out[0] = l0 - lse;
    out[1] = l1 - lse;
  }
}

// ---------------------------------------------------------------------------
extern "C" void kernel_launch(void* const* d_in, const int* in_sizes, int n_in,
                              void* d_out, int out_size, void* d_ws, size_t ws_size,
                              hipStream_t stream) {
  const int*   inputs = (const int*)  d_in[0];
  const float* hx     = (const float*)d_in[1];
  const float* emb    = (const float*)d_in[2];
  const float* w_ih   = (const float*)d_in[3];
  const float* w_hh   = (const float*)d_in[4];
  const float* b_ih   = (const float*)d_in[5];
  const float* b_hh   = (const float*)d_in[6];
  const float* w_out  = (const float*)d_in[7];
  const float* b_out  = (const float*)d_in[8];
  float* out = (float*)d_out;

  float* GI = (float*)d_ws;                                   // 3 MB
  unsigned long long* bufU =
      (unsigned long long*)((char*)d_ws + (size_t)NVOCAB * G3 * 4); // 32 KB
  unsigned* done = (unsigned*)(bufU + 2 * HID);               // 257*16 dwords

  gi_precompute<<<dim3(G3/64, NVOCAB/64), 256, 0, stream>>>(emb, w_ih, b_ih, GI);

  void* args[] = { (void*)&GI, (void*)&w_hh, (void*)&b_hh, (void*)&inputs,
                   (void*)&w_out, (void*)&b_out, (void*)&bufU, (void*)&done,
                   (void*)&out, (void*)&hx };
  hipError_t ce = hipLaunchCooperativeKernel((void*)gru_reg, dim3(NBLK), dim3(256),
                                             args, 0, stream);
  if (ce != hipSuccess) {
    float* h0 = (float*)bufU;          // fallback reuses exchange region
    float* h1 = h0 + HID;
    const float* hin = hx;
    for (int t = 0; t < SEQ; ++t) {
      float* hout = (t & 1) ? h1 : h0;
      gru_step_fb<<<512, 256, 0, stream>>>(GI, w_hh, b_hh, inputs, t, hin, hout);
      hin = hout;
    }
    gru_out_fb<<<1, 128, 0, stream>>>(hin, w_out, b_out, out);
  }
}